// Round 14
// baseline (82.425 us; speedup 1.0000x reference)
//
#include <hip/hip_runtime.h>

#define S_LEN 4096
#define B_SZ 8
#define HN_OFF 8388608      // 8*4096*256
#define CPROWS 544          // 8-elem rows per parity copy (zero-padded past 4096)

typedef __attribute__((ext_vector_type(8))) short short8;
typedef __attribute__((ext_vector_type(4))) float f32x4;

typedef const __attribute__((address_space(1))) unsigned int as1_u32;
typedef __attribute__((address_space(3))) unsigned int as3_u32;

__device__ __forceinline__ void gload16(const short* g, short* l) {
  __builtin_amdgcn_global_load_lds((as1_u32*)g, (as3_u32*)l, 16, 0, 0);
}

__device__ __forceinline__ short f2bf(float f) {
  union { float f; unsigned u; } v; v.f = f;
  unsigned r = v.u + 0x7FFFu + ((v.u >> 16) & 1u);
  return (short)(r >> 16);
}

#define MFMA16(Aa, Bb) \
  acc[0][0] = __builtin_amdgcn_mfma_f32_16x16x32_bf16(Aa##0, Bb##0, acc[0][0], 0, 0, 0); \
  acc[0][1] = __builtin_amdgcn_mfma_f32_16x16x32_bf16(Aa##0, Bb##1, acc[0][1], 0, 0, 0); \
  acc[0][2] = __builtin_amdgcn_mfma_f32_16x16x32_bf16(Aa##0, Bb##2, acc[0][2], 0, 0, 0); \
  acc[0][3] = __builtin_amdgcn_mfma_f32_16x16x32_bf16(Aa##0, Bb##3, acc[0][3], 0, 0, 0); \
  acc[1][0] = __builtin_amdgcn_mfma_f32_16x16x32_bf16(Aa##1, Bb##0, acc[1][0], 0, 0, 0); \
  acc[1][1] = __builtin_amdgcn_mfma_f32_16x16x32_bf16(Aa##1, Bb##1, acc[1][1], 0, 0, 0); \
  acc[1][2] = __builtin_amdgcn_mfma_f32_16x16x32_bf16(Aa##1, Bb##2, acc[1][2], 0, 0, 0); \
  acc[1][3] = __builtin_amdgcn_mfma_f32_16x16x32_bf16(Aa##1, Bb##3, acc[1][3], 0, 0, 0); \
  acc[2][0] = __builtin_amdgcn_mfma_f32_16x16x32_bf16(Aa##2, Bb##0, acc[2][0], 0, 0, 0); \
  acc[2][1] = __builtin_amdgcn_mfma_f32_16x16x32_bf16(Aa##2, Bb##1, acc[2][1], 0, 0, 0); \
  acc[2][2] = __builtin_amdgcn_mfma_f32_16x16x32_bf16(Aa##2, Bb##2, acc[2][2], 0, 0, 0); \
  acc[2][3] = __builtin_amdgcn_mfma_f32_16x16x32_bf16(Aa##2, Bb##3, acc[2][3], 0, 0, 0); \
  acc[3][0] = __builtin_amdgcn_mfma_f32_16x16x32_bf16(Aa##3, Bb##0, acc[3][0], 0, 0, 0); \
  acc[3][1] = __builtin_amdgcn_mfma_f32_16x16x32_bf16(Aa##3, Bb##1, acc[3][1], 0, 0, 0); \
  acc[3][2] = __builtin_amdgcn_mfma_f32_16x16x32_bf16(Aa##3, Bb##2, acc[3][2], 0, 0, 0); \
  acc[3][3] = __builtin_amdgcn_mfma_f32_16x16x32_bf16(Aa##3, Bb##3, acc[3][3], 0, 0, 0);

// K1 fused prep (R13, unchanged):
__global__ __launch_bounds__(256) void k_prep(const float* __restrict__ x,
                                              const float* __restrict__ Wu,
                                              const float* __restrict__ bu,
                                              const float* __restrict__ H,
                                              const float* __restrict__ Wh,
                                              short* __restrict__ cp,
                                              short* __restrict__ xb,
                                              short* __restrict__ Ht,
                                              short* __restrict__ wht) {
  int bx = blockIdx.x;
  if (bx >= 8520) {
    int j = (bx - 8520) * 256 + threadIdx.x;
    if (j < 256 * 384) {
      int n = j / 384, k = j % 384;
      wht[j] = f2bf(Wh[k * 256 + n]);
    }
    return;
  }
  if (bx >= 8264) {
    __shared__ short tile[64][72];
    int bx2 = bx - 8264;                 // 256 = tt(64) * qt(4)
    int t0 = (bx2 >> 2) << 6, q0 = (bx2 & 3) << 6;
    int tid = threadIdx.x;
    int r = tid >> 2, c0 = (tid & 3) << 4;
    const float* src = H + (size_t)(q0 + r) * S_LEN + t0 + c0;
    #pragma unroll
    for (int v4 = 0; v4 < 4; ++v4) {
      float4 hv = *(const float4*)(src + 4 * v4);
      tile[r][c0 + 4 * v4]     = f2bf(hv.x);
      tile[r][c0 + 4 * v4 + 1] = f2bf(hv.y);
      tile[r][c0 + 4 * v4 + 2] = f2bf(hv.z);
      tile[r][c0 + 4 * v4 + 3] = f2bf(hv.w);
    }
    __syncthreads();
    int s2 = tid >> 2, qc = (tid & 3) << 4;
    short8 o0, o1;
    #pragma unroll
    for (int j2 = 0; j2 < 8; ++j2) {
      o0[j2] = tile[qc + j2][s2];
      o1[j2] = tile[qc + 8 + j2][s2];
    }
    short* dst = Ht + (size_t)(t0 + s2) * 256 + q0 + qc;
    *(short8*)dst       = o0;
    *(short8*)(dst + 8) = o1;
    return;
  }
  if (bx >= 8192) {
    int idx = (bx - 8192) * 256 + threadIdx.x;
    if (idx < 18432) {
      int j = idx & 7;
      int r = 508 + ((idx >> 3) % 36);
      int rem = (idx >> 3) / 36;
      int p = rem & 7;
      int b = rem >> 3;
      int e = 8 * r + p + j;
      if (e >= S_LEN)
        cp[((size_t)(b * 8 + p) * CPROWS + r) * 8 + j] = 0;
    }
    return;
  }
  int row = bx * 4 + (threadIdx.x >> 6);   // b*4096 + t
  int l = threadIdx.x & 63;
  float2 xv = *(const float2*)(x + (size_t)row * 128 + 2 * l);
  float2 wv = *(const float2*)(Wu + 2 * l);
  float s = xv.x * wv.x + xv.y * wv.y;
  #pragma unroll
  for (int m = 32; m >= 1; m >>= 1) s += __shfl_xor(s, m, 64);
  unsigned pack = (((unsigned)f2bf(xv.y) & 0xFFFFu) << 16) | ((unsigned)f2bf(xv.x) & 0xFFFFu);
  *(unsigned*)(xb + (size_t)row * 128 + 2 * l) = pack;
  float v = s + bu[0];
  v = v > 0.0f ? v : 0.0f;
  short vb = f2bf(v);
  if (l < 8) {
    int t = row & (S_LEN - 1);
    int b = row >> 12;
    int e = (S_LEN - 1) - t;
    int p = l;
    if (e >= p) {
      int d = e - p;
      cp[((size_t)(b * 8 + p) * CPROWS + (d >> 3)) * 8 + (d & 7)] = vb;
    }
  }
}

// K2: Gt[n][t] = sum_q Wh[q,n]*H[q,t] (R13, unchanged)
__global__ __launch_bounds__(256) void k_g(const short* __restrict__ wht,
                                           const short* __restrict__ Ht,
                                           short* __restrict__ Gt) {
  int nt = blockIdx.x & 1, tt = blockIdx.x >> 1;
  int n0 = nt << 7, t0 = tt << 7;
  int tid = threadIdx.x;
  int lane = tid & 63, wid = tid >> 6;
  int wr = wid >> 1, wc = wid & 1;
  int lm = lane & 15, kg = lane >> 4;

  const short* Abase = wht + (size_t)(n0 + wr * 64 + lm) * 384 + 8 * kg;
  const short* Bbase = Ht  + (size_t)(t0 + wc * 64 + lm) * 256 + 8 * kg;

  f32x4 acc[4][4];
  #pragma unroll
  for (int ii = 0; ii < 4; ++ii)
    #pragma unroll
    for (int jn = 0; jn < 4; ++jn)
      acc[ii][jn] = (f32x4){0.0f, 0.0f, 0.0f, 0.0f};

  #pragma unroll
  for (int c = 0; c < 4; ++c) {
    short8 a[8], bf[8];
    #pragma unroll
    for (int mf = 0; mf < 4; ++mf)
      #pragma unroll
      for (int ks = 0; ks < 2; ++ks)
        a[mf * 2 + ks] = *(const short8*)(Abase + mf * 16 * 384 + c * 64 + ks * 32);
    #pragma unroll
    for (int nf = 0; nf < 4; ++nf)
      #pragma unroll
      for (int ks = 0; ks < 2; ++ks)
        bf[nf * 2 + ks] = *(const short8*)(Bbase + nf * 16 * 256 + c * 64 + ks * 32);
    #pragma unroll
    for (int ks = 0; ks < 2; ++ks)
      #pragma unroll
      for (int mf = 0; mf < 4; ++mf)
        #pragma unroll
        for (int nf = 0; nf < 4; ++nf)
          acc[mf][nf] = __builtin_amdgcn_mfma_f32_16x16x32_bf16(a[mf * 2 + ks], bf[nf * 2 + ks], acc[mf][nf], 0, 0, 0);
  }

  #pragma unroll
  for (int mf = 0; mf < 4; ++mf)
    #pragma unroll
    for (int nf = 0; nf < 4; ++nf)
      #pragma unroll
      for (int j = 0; j < 4; ++j) {
        int n = n0 + wr * 64 + mf * 16 + kg * 4 + j;
        int t = t0 + wc * 64 + nf * 16 + lm;
        Gt[(size_t)n * S_LEN + t] = f2bf(acc[mf][nf][j]);
      }
}

// K3 fused, phase-interleaved: h[s,n] = relu(Toeplitz(u)@Gt^T + x@Whx + bh).
// BK=64, ring-4 (R10 slot discipline + algebra verbatim), counted vmcnt at
// chunk top only (5/4/0 = loads of chunk c+1 in flight); chunk body split
// into 2 ks-sub-phases: {8 ds_read || half STAGE(c+2)} barrier {16 MFMA
// setprio-wrapped} barrier. x-part = 2 extra ring chunks (x tile in B-slots,
// Whx frags from L2 per phase).
__global__ __launch_bounds__(256, 2) void k_fused(const short* __restrict__ cp,
                                                  const short* __restrict__ Gt,
                                                  const short* __restrict__ xb,
                                                  const short* __restrict__ wht,
                                                  const float* __restrict__ bh,
                                                  float* __restrict__ out) {
  __shared__ __attribute__((aligned(16))) short Bt[4][128 * 64];  // 64 KB
  __shared__ __attribute__((aligned(16))) short Aw[4][2048];      // 16 KB

  int i = blockIdx.x;                 // 512 blocks, R10 balance map
  int j  = i >> 1, lo = i & 1;
  int jj = j & 127;
  int fj = (j >> 7) ? (31 - (jj >> 3)) : (jj >> 3);
  int st = lo ? (31 - fj) : fj;
  int nt = lo;
  int b  = j & 7;
  int s0 = st << 7, n0 = nt << 7;

  int tid = threadIdx.x;
  int lane = tid & 63, wid = tid >> 6;
  int wr = wid >> 1, wc = wid & 1;      // wave tile 64(s) x 64(n)
  int lm = lane & 15, kg = lane >> 4;
  int l3 = lane >> 3, l7 = lane & 7;
  int lm7 = lm & 7;

  // staging sources (R10 algebra; Hb->Gt)
  const short* bSrc = Gt + (size_t)(n0 + wid * 32 + l3) * S_LEN + ((l7 ^ l3) << 3);
  int asbase = 496 - 16 * st;
  const short* aSrc = cp + ((size_t)(b * 8 + (l7 ^ l3)) * CPROWS + asbase + wid * 8 + l3) * 8;
  const short* xSrc = xb + (size_t)(b * S_LEN + s0 + wid * 32 + l3) * 128 + ((l7 ^ l3) << 3);

  // A-frag offsets (R10 XOR swizzle + dedup)
  int dbase = 127 - 64 * wr - lm + 8 * kg;
  int aof[6];
  #pragma unroll
  for (int ii = 0; ii < 6; ++ii) {
    int d = (ii < 4) ? (dbase - 16 * ii) : (dbase + 96 - 16 * ii);
    aof[ii] = ((d & ~7) | ((d & 7) ^ ((d >> 3) & 7))) << 3;
  }
  // B-frag offsets (R10)
  int bRow = (wc * 64 + lm) * 64;
  int bof[8];
  #pragma unroll
  for (int nf = 0; nf < 4; ++nf)
    #pragma unroll
    for (int ks = 0; ks < 2; ++ks)
      bof[nf * 2 + ks] = bRow + nf * 1024 + (((ks << 5) + (kg << 3)) ^ (lm7 << 3));
  // x A-frag offsets (k_gemm2-proven 64-wide pattern, rows = s)
  int xof[8];
  #pragma unroll
  for (int mf = 0; mf < 4; ++mf)
    #pragma unroll
    for (int ks = 0; ks < 2; ++ks)
      xof[mf * 2 + ks] = (wr * 64 + mf * 16 + lm) * 64 + (((ks << 5) + (kg << 3)) ^ (lm7 << 3));
  // Whx B-frag global base: row n0+wc*64+nf*16+lm, k = 256 + cx*64 + ks*32 + kg*8
  const short* wxBase = wht + (size_t)(n0 + wc * 64 + lm) * 384 + 256 + 8 * kg;

  f32x4 acc[4][4];
  #pragma unroll
  for (int ii = 0; ii < 4; ++ii)
    #pragma unroll
    for (int jn = 0; jn < 4; ++jn)
      acc[ii][jn] = (f32x4){0.0f, 0.0f, 0.0f, 0.0f};

  int T  = 2 * st + 2;                // Toeplitz chunks
  int NC = T + 2;                     // + 2 x-chunks

  auto STAGE_T = [&](int cc, int part) {
    int slot = cc & 3;
    if (part == 0) {
      gload16(bSrc + cc * 64,                         &Bt[slot][(wid * 32) * 64]);
      gload16(bSrc + (size_t)8 * S_LEN + cc * 64,     &Bt[slot][(wid * 32 + 8) * 64]);
      gload16(aSrc + cc * 64,                         &Aw[slot][wid * 512]);
    } else {
      gload16(bSrc + (size_t)16 * S_LEN + cc * 64,    &Bt[slot][(wid * 32 + 16) * 64]);
      gload16(bSrc + (size_t)24 * S_LEN + cc * 64,    &Bt[slot][(wid * 32 + 24) * 64]);
    }
  };
  auto STAGE_X = [&](int cc, int part) {
    int slot = cc & 3;
    int co = (cc - T) * 64;
    if (part == 0) {
      gload16(xSrc + co,              &Bt[slot][(wid * 32) * 64]);
      gload16(xSrc + co + 8 * 128,    &Bt[slot][(wid * 32 + 8) * 64]);
    } else {
      gload16(xSrc + co + 16 * 128,   &Bt[slot][(wid * 32 + 16) * 64]);
      gload16(xSrc + co + 24 * 128,   &Bt[slot][(wid * 32 + 24) * 64]);
    }
  };

  // prologue: chunks 0 and 1 fully staged (T >= 2 always)
  STAGE_T(0, 0); STAGE_T(0, 1);
  STAGE_T(1, 0); STAGE_T(1, 1);

  for (int c = 0; c < NC; ++c) {
    // chunk-top counted vmcnt + barrier: only STAGE(c+1) in flight
    if (c + 1 < T)       asm volatile("s_waitcnt vmcnt(5)\n\ts_barrier" ::: "memory");
    else if (c + 1 < NC) asm volatile("s_waitcnt vmcnt(4)\n\ts_barrier" ::: "memory");
    else                 asm volatile("s_waitcnt vmcnt(0)\n\ts_barrier" ::: "memory");

    const short* BtB = &Bt[c & 3][0];
    if (c < T) {
      const short* AwB = &Aw[c & 3][0];
      // ---- phase 0 (ks=0) ----
      short8 A0 = *(const short8*)(AwB + aof[0]);
      short8 A1 = *(const short8*)(AwB + aof[1]);
      short8 A2 = *(const short8*)(AwB + aof[2]);
      short8 A3 = *(const short8*)(AwB + aof[3]);
      short8 B0 = *(const short8*)(BtB + bof[0]);
      short8 B1 = *(const short8*)(BtB + bof[2]);
      short8 B2 = *(const short8*)(BtB + bof[4]);
      short8 B3 = *(const short8*)(BtB + bof[6]);
      if (c + 2 < T) STAGE_T(c + 2, 0);
      else if (c + 2 < NC) STAGE_X(c + 2, 0);
      asm volatile("s_barrier" ::: "memory");
      __builtin_amdgcn_s_setprio(1);
      MFMA16(A, B)
      __builtin_amdgcn_s_setprio(0);
      asm volatile("s_barrier" ::: "memory");
      // ---- phase 1 (ks=1) ----
      short8 C0 = *(const short8*)(AwB + aof[4]);
      short8 C1 = *(const short8*)(AwB + aof[5]);
      short8 C2 = A0, C3 = A1;
      short8 D0 = *(const short8*)(BtB + bof[1]);
      short8 D1 = *(const short8*)(BtB + bof[3]);
      short8 D2 = *(const short8*)(BtB + bof[5]);
      short8 D3 = *(const short8*)(BtB + bof[7]);
      if (c + 2 < T) STAGE_T(c + 2, 1);
      else if (c + 2 < NC) STAGE_X(c + 2, 1);
      asm volatile("s_barrier" ::: "memory");
      __builtin_amdgcn_s_setprio(1);
      MFMA16(C, D)
      __builtin_amdgcn_s_setprio(0);
      asm volatile("s_barrier" ::: "memory");
    } else {
      int co = (c - T) * 64;
      // ---- phase 0 (ks=0) ----
      short8 A0 = *(const short8*)(BtB + xof[0]);
      short8 A1 = *(const short8*)(BtB + xof[2]);
      short8 A2 = *(const short8*)(BtB + xof[4]);
      short8 A3 = *(const short8*)(BtB + xof[6]);
      short8 B0 = *(const short8*)(wxBase + co);
      short8 B1 = *(const short8*)(wxBase + 16 * 384 + co);
      short8 B2 = *(const short8*)(wxBase + 32 * 384 + co);
      short8 B3 = *(const short8*)(wxBase + 48 * 384 + co);
      asm volatile("s_barrier" ::: "memory");
      __builtin_amdgcn_s_setprio(1);
      MFMA16(A, B)
      __builtin_amdgcn_s_setprio(0);
      asm volatile("s_barrier" ::: "memory");
      // ---- phase 1 (ks=1) ----
      short8 C0 = *(const short8*)(BtB + xof[1]);
      short8 C1 = *(const short8*)(BtB + xof[3]);
      short8 C2 = *(const short8*)(BtB + xof[5]);
      short8 C3 = *(const short8*)(BtB + xof[7]);
      short8 D0 = *(const short8*)(wxBase + co + 32);
      short8 D1 = *(const short8*)(wxBase + 16 * 384 + co + 32);
      short8 D2 = *(const short8*)(wxBase + 32 * 384 + co + 32);
      short8 D3 = *(const short8*)(wxBase + 48 * 384 + co + 32);
      asm volatile("s_barrier" ::: "memory");
      __builtin_amdgcn_s_setprio(1);
      MFMA16(C, D)
      __builtin_amdgcn_s_setprio(0);
      asm volatile("s_barrier" ::: "memory");
    }
  }

  // Epilogue: bias + relu + f32 store (+ h_n for s==4095)
  #pragma unroll
  for (int mf = 0; mf < 4; ++mf)
    #pragma unroll
    for (int nf = 0; nf < 4; ++nf) {
      int n = n0 + wc * 64 + nf * 16 + lm;
      float bias = bh[n];
      #pragma unroll
      for (int j2 = 0; j2 < 4; ++j2) {
        int s = s0 + wr * 64 + mf * 16 + kg * 4 + j2;
        float v = acc[mf][nf][j2] + bias;
        v = v > 0.0f ? v : 0.0f;
        out[(size_t)(b * S_LEN + s) * 256 + n] = v;
        if (s == S_LEN - 1)
          out[HN_OFF + b * 256 + n] = v;
      }
    }
}

extern "C" void kernel_launch(void* const* d_in, const int* in_sizes, int n_in,
                              void* d_out, int out_size, void* d_ws, size_t ws_size,
                              hipStream_t stream) {
  const float* x  = (const float*)d_in[0];
  const float* Wu = (const float*)d_in[1];
  const float* bu = (const float*)d_in[2];
  const float* Wh = (const float*)d_in[3];
  const float* bh = (const float*)d_in[4];
  const float* H  = (const float*)d_in[5];
  float* out = (float*)d_out;

  char* ws = (char*)d_ws;
  short* cp  = (short*)(ws);                       // 557056 B
  short* wht = (short*)(ws + 557056);              // 196608 B
  short* xb  = (short*)(ws + 753664);              // 8388608 B
  short* Ht  = (short*)(ws + 9142272);             // 2097152 B
  short* Gt  = (short*)(ws + 11239424);            // 2097152 B (end 13336576)

  k_prep<<<8904, 256, 0, stream>>>(x, Wu, bu, H, Wh, cp, xb, Ht, wht);
  k_g   <<<64,   256, 0, stream>>>(wht, Ht, Gt);
  k_fused<<<512, 256, 0, stream>>>(cp, Gt, xb, wht, bh, out);
}

// Round 15
// 76.337 us; speedup vs baseline: 1.0797x; 1.0797x over previous
//
#include <hip/hip_runtime.h>

#define S_LEN 4096
#define B_SZ 8
#define HN_OFF 8388608      // 8*4096*256
#define CPROWS 544          // 8-elem rows per parity copy (zero-padded past 4096)

typedef __attribute__((ext_vector_type(8))) short short8;
typedef __attribute__((ext_vector_type(4))) float f32x4;

typedef const __attribute__((address_space(1))) unsigned int as1_u32;
typedef __attribute__((address_space(3))) unsigned int as3_u32;

__device__ __forceinline__ void gload16(const short* g, short* l) {
  __builtin_amdgcn_global_load_lds((as1_u32*)g, (as3_u32*)l, 16, 0, 0);
}

__device__ __forceinline__ short f2bf(float f) {
  union { float f; unsigned u; } v; v.f = f;
  unsigned r = v.u + 0x7FFFu + ((v.u >> 16) & 1u);
  return (short)(r >> 16);
}

// K1 fused prep (R13, unchanged):
__global__ __launch_bounds__(256) void k_prep(const float* __restrict__ x,
                                              const float* __restrict__ Wu,
                                              const float* __restrict__ bu,
                                              const float* __restrict__ H,
                                              const float* __restrict__ Wh,
                                              short* __restrict__ cp,
                                              short* __restrict__ xb,
                                              short* __restrict__ Ht,
                                              short* __restrict__ wht) {
  int bx = blockIdx.x;
  if (bx >= 8520) {
    int j = (bx - 8520) * 256 + threadIdx.x;
    if (j < 256 * 384) {
      int n = j / 384, k = j % 384;
      wht[j] = f2bf(Wh[k * 256 + n]);
    }
    return;
  }
  if (bx >= 8264) {
    __shared__ short tile[64][72];
    int bx2 = bx - 8264;                 // 256 = tt(64) * qt(4)
    int t0 = (bx2 >> 2) << 6, q0 = (bx2 & 3) << 6;
    int tid = threadIdx.x;
    int r = tid >> 2, c0 = (tid & 3) << 4;
    const float* src = H + (size_t)(q0 + r) * S_LEN + t0 + c0;
    #pragma unroll
    for (int v4 = 0; v4 < 4; ++v4) {
      float4 hv = *(const float4*)(src + 4 * v4);
      tile[r][c0 + 4 * v4]     = f2bf(hv.x);
      tile[r][c0 + 4 * v4 + 1] = f2bf(hv.y);
      tile[r][c0 + 4 * v4 + 2] = f2bf(hv.z);
      tile[r][c0 + 4 * v4 + 3] = f2bf(hv.w);
    }
    __syncthreads();
    int s2 = tid >> 2, qc = (tid & 3) << 4;
    short8 o0, o1;
    #pragma unroll
    for (int j2 = 0; j2 < 8; ++j2) {
      o0[j2] = tile[qc + j2][s2];
      o1[j2] = tile[qc + 8 + j2][s2];
    }
    short* dst = Ht + (size_t)(t0 + s2) * 256 + q0 + qc;
    *(short8*)dst       = o0;
    *(short8*)(dst + 8) = o1;
    return;
  }
  if (bx >= 8192) {
    int idx = (bx - 8192) * 256 + threadIdx.x;
    if (idx < 18432) {
      int j = idx & 7;
      int r = 508 + ((idx >> 3) % 36);
      int rem = (idx >> 3) / 36;
      int p = rem & 7;
      int b = rem >> 3;
      int e = 8 * r + p + j;
      if (e >= S_LEN)
        cp[((size_t)(b * 8 + p) * CPROWS + r) * 8 + j] = 0;
    }
    return;
  }
  int row = bx * 4 + (threadIdx.x >> 6);   // b*4096 + t
  int l = threadIdx.x & 63;
  float2 xv = *(const float2*)(x + (size_t)row * 128 + 2 * l);
  float2 wv = *(const float2*)(Wu + 2 * l);
  float s = xv.x * wv.x + xv.y * wv.y;
  #pragma unroll
  for (int m = 32; m >= 1; m >>= 1) s += __shfl_xor(s, m, 64);
  unsigned pack = (((unsigned)f2bf(xv.y) & 0xFFFFu) << 16) | ((unsigned)f2bf(xv.x) & 0xFFFFu);
  *(unsigned*)(xb + (size_t)row * 128 + 2 * l) = pack;
  float v = s + bu[0];
  v = v > 0.0f ? v : 0.0f;
  short vb = f2bf(v);
  if (l < 8) {
    int t = row & (S_LEN - 1);
    int b = row >> 12;
    int e = (S_LEN - 1) - t;
    int p = l;
    if (e >= p) {
      int d = e - p;
      cp[((size_t)(b * 8 + p) * CPROWS + (d >> 3)) * 8 + (d & 7)] = vb;
    }
  }
}

// K2: Gt[n][t] = sum_q Wh[q,n]*H[q,t] (R13, unchanged)
__global__ __launch_bounds__(256) void k_g(const short* __restrict__ wht,
                                           const short* __restrict__ Ht,
                                           short* __restrict__ Gt) {
  int nt = blockIdx.x & 1, tt = blockIdx.x >> 1;
  int n0 = nt << 7, t0 = tt << 7;
  int tid = threadIdx.x;
  int lane = tid & 63, wid = tid >> 6;
  int wr = wid >> 1, wc = wid & 1;
  int lm = lane & 15, kg = lane >> 4;

  const short* Abase = wht + (size_t)(n0 + wr * 64 + lm) * 384 + 8 * kg;
  const short* Bbase = Ht  + (size_t)(t0 + wc * 64 + lm) * 256 + 8 * kg;

  f32x4 acc[4][4];
  #pragma unroll
  for (int ii = 0; ii < 4; ++ii)
    #pragma unroll
    for (int jn = 0; jn < 4; ++jn)
      acc[ii][jn] = (f32x4){0.0f, 0.0f, 0.0f, 0.0f};

  #pragma unroll
  for (int c = 0; c < 4; ++c) {
    short8 a[8], bf[8];
    #pragma unroll
    for (int mf = 0; mf < 4; ++mf)
      #pragma unroll
      for (int ks = 0; ks < 2; ++ks)
        a[mf * 2 + ks] = *(const short8*)(Abase + mf * 16 * 384 + c * 64 + ks * 32);
    #pragma unroll
    for (int nf = 0; nf < 4; ++nf)
      #pragma unroll
      for (int ks = 0; ks < 2; ++ks)
        bf[nf * 2 + ks] = *(const short8*)(Bbase + nf * 16 * 256 + c * 64 + ks * 32);
    #pragma unroll
    for (int ks = 0; ks < 2; ++ks)
      #pragma unroll
      for (int mf = 0; mf < 4; ++mf)
        #pragma unroll
        for (int nf = 0; nf < 4; ++nf)
          acc[mf][nf] = __builtin_amdgcn_mfma_f32_16x16x32_bf16(a[mf * 2 + ks], bf[nf * 2 + ks], acc[mf][nf], 0, 0, 0);
  }

  #pragma unroll
  for (int mf = 0; mf < 4; ++mf)
    #pragma unroll
    for (int nf = 0; nf < 4; ++nf)
      #pragma unroll
      for (int j = 0; j < 4; ++j) {
        int n = n0 + wr * 64 + mf * 16 + kg * 4 + j;
        int t = t0 + wc * 64 + nf * 16 + lm;
        Gt[(size_t)n * S_LEN + t] = f2bf(acc[mf][nf][j]);
      }
}

// K3 fused, 8-wave equal-work blocks:
// h[s,n] = relu(Toeplitz(u)@Gt^T + x@Whx + bh). 256 blocks x 512 threads.
// Block = (kk,nt,b): computes tile st=31-kk then st=kk (in-block pairing) ->
// every block EXACTLY 35 BK-128 chunks (incl. 2 x-chunks): perfect balance,
// no placement assumptions, and 8 waves = 2 waves/SIMD even when solo (the
// fast regime; 4-wave blocks drop to 1/SIMD when their partner drains).
// Waves 2Mx4N: wave tile 64(s) x 32(n), acc[4][2]. Ring-2, 1 barrier/chunk
// (R12/R13-proven stage-after-barrier). A staged by waves 0-3 only.
// LDS padded >80KB to pin 1 block/CU.
__global__ __launch_bounds__(512, 2) void k_fused(const short* __restrict__ cp,
                                                  const short* __restrict__ Gt,
                                                  const short* __restrict__ xb,
                                                  const short* __restrict__ wht,
                                                  const float* __restrict__ bh,
                                                  float* __restrict__ out) {
  __shared__ __attribute__((aligned(16))) short Bt[2][128 * 128];  // 64 KB
  __shared__ __attribute__((aligned(16))) short Aw[2][6144];       // 24 KB (use 2048; pad pins 1 blk/CU)

  int i = blockIdx.x;                 // 256 = kk(16) * nt(2) * b(8)
  int kk = i >> 4;
  int nt = i & 1;
  int b  = (i >> 1) & 7;
  int n0 = nt << 7;

  int tid = threadIdx.x;
  int lane = tid & 63, wid = tid >> 6;   // 8 waves
  int wr = wid >> 2, wc = wid & 3;       // wr: s-half(64); wc: n-quarter(32)
  int lm = lane & 15, kg = lane >> 4;
  int l3 = lane >> 3, l7 = lane & 7;
  int lm7 = lm & 7;

  // B staging: per wave 16 rows (n). Rows wid*16 + 8e + {kg | 4+kg}; source
  // col chunk pre-swizzled by row&7 (lm^kg / lm^kg^4); linear LDS dest.
  const short* bS0 = Gt + (size_t)(n0 + wid * 16 + kg) * S_LEN + ((lm ^ kg) << 3);
  const short* bS1 = Gt + (size_t)(n0 + wid * 16 + 4 + kg) * S_LEN + ((lm ^ (kg ^ 4)) << 3);

  // A-frag swizzled offsets (R13 BK=128 dedup): frag(mf,ks) -> v=2ks-mf+3
  int dbase = 127 - 64 * wr - lm + 8 * kg;
  int aof[10];
  #pragma unroll
  for (int v = 0; v < 10; ++v) {
    int d = dbase + 16 * v - 48;
    aof[v] = ((d & ~7) | ((d & 7) ^ ((d >> 3) & 7))) << 3;   // shorts
  }

  // B-frag offsets: row wc*32 + nf*16 + lm (nf 0..1), data chunk 4ks+kg
  int bof[8];
  #pragma unroll
  for (int nf = 0; nf < 2; ++nf)
    #pragma unroll
    for (int ks = 0; ks < 4; ++ks)
      bof[nf * 4 + ks] = (wc * 32 + nf * 16 + lm) * 128 + (((4 * ks + kg) ^ lm7) << 3);

  // x-chunk A-frag offsets (rows s of staged x tile)
  int xof[16];
  #pragma unroll
  for (int mf = 0; mf < 4; ++mf)
    #pragma unroll
    for (int ks = 0; ks < 4; ++ks)
      xof[mf * 4 + ks] = (wr * 64 + mf * 16 + lm) * 128 + (((4 * ks + kg) ^ lm7) << 3);

  // Whx B-frag global base: row n0+wc*32+nf*16+lm, k = 256 + 32ks + 8kg
  const short* wxBase = wht + (size_t)(n0 + wc * 32 + lm) * 384 + 256 + 8 * kg;

  for (int ph = 0; ph < 2; ++ph) {
    int st = ph ? kk : (31 - kk);
    int s0 = st << 7;
    int asbase = 496 - 16 * st;
    const short* aSrc = cp + ((size_t)(b * 8 + (l7 ^ l3)) * CPROWS + asbase + wid * 8 + l3) * 8;
    const short* xR0 = xb + (size_t)(b * S_LEN + s0 + wid * 16 + kg) * 128 + ((lm ^ kg) << 3);
    const short* xR1 = xb + (size_t)(b * S_LEN + s0 + wid * 16 + 4 + kg) * 128 + ((lm ^ (kg ^ 4)) << 3);

    int NCt = st + 1;          // Toeplitz BK-128 chunks
    int NCp = NCt + 1;         // + x chunk

    f32x4 acc[4][2];
    #pragma unroll
    for (int ii = 0; ii < 4; ++ii)
      #pragma unroll
      for (int jn = 0; jn < 2; ++jn)
        acc[ii][jn] = (f32x4){0.0f, 0.0f, 0.0f, 0.0f};

    auto STAGE_T = [&](int cc) {
      int slot = cc & 1;
      int coff = cc * 128;
      #pragma unroll
      for (int e = 0; e < 2; ++e) {
        gload16(bS0 + (size_t)(8 * e) * S_LEN + coff, &Bt[slot][(wid * 16 + 8 * e) * 128]);
        gload16(bS1 + (size_t)(8 * e) * S_LEN + coff, &Bt[slot][(wid * 16 + 8 * e + 4) * 128]);
      }
      if (wid < 4) gload16(aSrc + coff, &Aw[slot][wid * 512]);
    };
    auto STAGE_X = [&]() {
      int slot = NCt & 1;
      #pragma unroll
      for (int e = 0; e < 2; ++e) {
        gload16(xR0 + (size_t)(8 * e) * 128, &Bt[slot][(wid * 16 + 8 * e) * 128]);
        gload16(xR1 + (size_t)(8 * e) * 128, &Bt[slot][(wid * 16 + 8 * e + 4) * 128]);
      }
    };

    // Phase prologue: drain previous phase's LDS reads before re-staging slot 0.
    asm volatile("s_waitcnt vmcnt(0) lgkmcnt(0)\n\ts_barrier" ::: "memory");
    STAGE_T(0);

    for (int c = 0; c < NCp; ++c) {
      asm volatile("s_waitcnt vmcnt(0) lgkmcnt(0)\n\ts_barrier" ::: "memory");
      if (c + 1 < NCt) STAGE_T(c + 1);
      else if (c + 1 < NCp) STAGE_X();

      if (c < NCt) {
        const short* AwB = &Aw[c & 1][0];
        const short* BtB = &Bt[c & 1][0];
        short8 A10[10];
        #pragma unroll
        for (int v = 0; v < 10; ++v) A10[v] = *(const short8*)(AwB + aof[v]);
        short8 Bf[8];
        #pragma unroll
        for (int ii = 0; ii < 8; ++ii) Bf[ii] = *(const short8*)(BtB + bof[ii]);
        __builtin_amdgcn_s_setprio(1);
        #pragma unroll
        for (int ks = 0; ks < 4; ++ks)
          #pragma unroll
          for (int mf = 0; mf < 4; ++mf)
            #pragma unroll
            for (int nf = 0; nf < 2; ++nf)
              acc[mf][nf] = __builtin_amdgcn_mfma_f32_16x16x32_bf16(
                  A10[2 * ks - mf + 3], Bf[nf * 4 + ks], acc[mf][nf], 0, 0, 0);
        __builtin_amdgcn_s_setprio(0);
      } else {
        const short* BtB = &Bt[NCt & 1][0];
        short8 Ax[16];
        #pragma unroll
        for (int ii = 0; ii < 16; ++ii) Ax[ii] = *(const short8*)(BtB + xof[ii]);
        short8 Bx[8];
        #pragma unroll
        for (int nf = 0; nf < 2; ++nf)
          #pragma unroll
          for (int ks = 0; ks < 4; ++ks)
            Bx[nf * 4 + ks] = *(const short8*)(wxBase + (size_t)nf * 16 * 384 + 32 * ks);
        __builtin_amdgcn_s_setprio(1);
        #pragma unroll
        for (int ks = 0; ks < 4; ++ks)
          #pragma unroll
          for (int mf = 0; mf < 4; ++mf)
            #pragma unroll
            for (int nf = 0; nf < 2; ++nf)
              acc[mf][nf] = __builtin_amdgcn_mfma_f32_16x16x32_bf16(
                  Ax[mf * 4 + ks], Bx[nf * 4 + ks], acc[mf][nf], 0, 0, 0);
        __builtin_amdgcn_s_setprio(0);
      }
    }

    // Epilogue (registers only): bias + relu + f32 store (+ h_n for s==4095)
    #pragma unroll
    for (int mf = 0; mf < 4; ++mf)
      #pragma unroll
      for (int nf = 0; nf < 2; ++nf) {
        int n = n0 + wc * 32 + nf * 16 + lm;
        float bias = bh[n];
        #pragma unroll
        for (int j2 = 0; j2 < 4; ++j2) {
          int s = s0 + wr * 64 + mf * 16 + kg * 4 + j2;
          float v = acc[mf][nf][j2] + bias;
          v = v > 0.0f ? v : 0.0f;
          out[(size_t)(b * S_LEN + s) * 256 + n] = v;
          if (s == S_LEN - 1)
            out[HN_OFF + b * 256 + n] = v;
        }
      }
  }
}

extern "C" void kernel_launch(void* const* d_in, const int* in_sizes, int n_in,
                              void* d_out, int out_size, void* d_ws, size_t ws_size,
                              hipStream_t stream) {
  const float* x  = (const float*)d_in[0];
  const float* Wu = (const float*)d_in[1];
  const float* bu = (const float*)d_in[2];
  const float* Wh = (const float*)d_in[3];
  const float* bh = (const float*)d_in[4];
  const float* H  = (const float*)d_in[5];
  float* out = (float*)d_out;

  char* ws = (char*)d_ws;
  short* cp  = (short*)(ws);                       // 557056 B
  short* wht = (short*)(ws + 557056);              // 196608 B
  short* xb  = (short*)(ws + 753664);              // 8388608 B
  short* Ht  = (short*)(ws + 9142272);             // 2097152 B
  short* Gt  = (short*)(ws + 11239424);            // 2097152 B (end 13336576)

  k_prep<<<8904, 256, 0, stream>>>(x, Wu, bu, H, Wh, cp, xb, Ht, wht);
  k_g   <<<64,   256, 0, stream>>>(wht, Ht, Gt);
  k_fused<<<256, 512, 0, stream>>>(cp, Gt, xb, wht, bh, out);
}